// Round 5
// baseline (540.300 us; speedup 1.0000x reference)
//
#include <hip/hip_runtime.h>
#include <stdint.h>

// ---------------------------------------------------------------------------
// GAT bot detector, 2-layer, N=50000 E=800000 IN=256 HID=128 HEADS=4.
// Round 5: precompute per-edge attention alpha in an edge-parallel kernel
// (packed (src, alpha) float2 planes per head); agg kernels become pure
// coalesced-alpha + row-gather + FMA with 8-pair unroll (16 gathers in
// flight). Sync-staged GEMMs kept (global_load_lds proved racy in r2).
// ---------------------------------------------------------------------------

typedef _Float16 f16;
typedef f16 f16x8 __attribute__((ext_vector_type(8)));
typedef f16 f16x4 __attribute__((ext_vector_type(4)));
typedef f16 f16x2 __attribute__((ext_vector_type(2)));
typedef float f32x4 __attribute__((ext_vector_type(4)));

// --------------------------- CSR construction ------------------------------

__global__ void detect_i64_kernel(const int* __restrict__ ei, int* __restrict__ flag) {
  if (threadIdx.x == 0 && blockIdx.x == 0) {
    int nz = 0;
    for (int i = 0; i < 256; ++i) nz |= ei[2 * i + 1];
    *flag = (nz == 0) ? 1 : 0;
  }
}

__global__ void hist_kernel(const int* __restrict__ ei, int E, int N,
                            const int* __restrict__ flagp, int* __restrict__ deg) {
  int idx = blockIdx.x * blockDim.x + threadIdx.x;
  int EA = E + N;
  if (idx >= EA) return;
  int dst;
  if (idx < E) {
    dst = (*flagp) ? ei[2 * ((size_t)E + idx)] : ei[(size_t)E + idx];
  } else {
    dst = idx - E;  // self loop
  }
  if ((unsigned)dst >= (unsigned)N) return;
  atomicAdd(&deg[dst], 1);
}

// 3-phase scan: per-block inclusive -> block-sums scan -> fixup.
__global__ __launch_bounds__(256) void scan1_kernel(const int* __restrict__ deg,
                                                    int* __restrict__ tmp,
                                                    int* __restrict__ bsum, int n) {
  __shared__ int sd[256];
  const int t = threadIdx.x;
  const int i = blockIdx.x * 256 + t;
  int x = (i < n) ? deg[i] : 0;
  sd[t] = x;
  __syncthreads();
  for (int off = 1; off < 256; off <<= 1) {
    int v = (t >= off) ? sd[t - off] : 0;
    __syncthreads();
    sd[t] += v;
    __syncthreads();
  }
  if (i < n) tmp[i] = sd[t];
  if (t == 255) bsum[blockIdx.x] = sd[255];
}

__global__ __launch_bounds__(256) void scan2_kernel(const int* __restrict__ bsum,
                                                    int* __restrict__ boff, int nb) {
  __shared__ int sd[256];
  const int t = threadIdx.x;
  int x = (t < nb) ? bsum[t] : 0;
  sd[t] = x;
  __syncthreads();
  for (int off = 1; off < 256; off <<= 1) {
    int v = (t >= off) ? sd[t - off] : 0;
    __syncthreads();
    sd[t] += v;
    __syncthreads();
  }
  if (t < nb) boff[t] = sd[t] - x;  // exclusive
}

__global__ void scan3_kernel(const int* __restrict__ deg, const int* __restrict__ tmp,
                             const int* __restrict__ boff, int* __restrict__ row_ptr,
                             int* __restrict__ cursor, int n) {
  int i = blockIdx.x * 256 + threadIdx.x;
  if (i >= n) return;
  int g = tmp[i] + boff[i >> 8];
  row_ptr[i + 1] = g;
  cursor[i] = g - deg[i];
  if (i == 0) row_ptr[0] = 0;
}

__global__ void scatter_kernel(const int* __restrict__ ei, int E, int N,
                               const int* __restrict__ flagp,
                               int* __restrict__ cursor, int* __restrict__ csr,
                               int* __restrict__ dstOf) {
  int idx = blockIdx.x * blockDim.x + threadIdx.x;
  int EA = E + N;
  if (idx >= EA) return;
  int src, dst;
  if (idx < E) {
    if (*flagp) { src = ei[2 * (size_t)idx]; dst = ei[2 * ((size_t)E + idx)]; }
    else        { src = ei[(size_t)idx];     dst = ei[(size_t)E + idx]; }
  } else {
    src = dst = idx - E;
  }
  if ((unsigned)dst >= (unsigned)N || (unsigned)src >= (unsigned)N) return;
  int pos = atomicAdd(&cursor[dst], 1);
  csr[pos] = src;
  dstOf[pos] = dst;
}

// --------------------------- f32 -> f16 convert ----------------------------
__global__ void cvt_f16_kernel(const float* __restrict__ src, f16* __restrict__ dst,
                               int srcRows, int dstRows, int cols, int gshift) {
  int idx = blockIdx.x * blockDim.x + threadIdx.x;
  int total = dstRows << gshift;
  if (idx >= total) return;
  int row = idx >> gshift;
  int col = (idx & ((1 << gshift) - 1)) * 4;
  float4 v = make_float4(0.f, 0.f, 0.f, 0.f);
  if (row < srcRows) v = *(const float4*)&src[(size_t)row * cols + col];
  f16x4 o = {(f16)v.x, (f16)v.y, (f16)v.z, (f16)v.w};
  *(f16x4*)&dst[(size_t)row * cols + col] = o;
}

// ------------------------------ f16 GEMM -----------------------------------
// C[M,Ncols] = A * B^T, sync staging (global vec load -> ds_write), XOR
// swizzle on 16B chunks to keep ds_read_b128 conflict-free.
template <int BM, int TPB>
__global__ __launch_bounds__(TPB) void gemm_f16_kernel(
    const f16* __restrict__ A, const f16* __restrict__ Bm, f16* __restrict__ C,
    int K, int Ncols) {
  __shared__ f16 lA[BM * 32];
  __shared__ f16 lB[128 * 32];
  const int tid = threadIdx.x;
  const int w = tid >> 6, lane = tid & 63;
  const int wm = w >> 1, wn = w & 1;
  const int rowBase = blockIdx.y * BM;
  const int colBase = blockIdx.x * 128;
  const int lrow = lane & 15, lk = lane >> 4;
  f32x4 acc[4][4];
#pragma unroll
  for (int i = 0; i < 4; ++i)
#pragma unroll
    for (int j = 0; j < 4; ++j) acc[i][j] = (f32x4){0.f, 0.f, 0.f, 0.f};

  for (int kv = 0; kv < K; kv += 32) {
    f16x8 stA[(BM * 4) / TPB], stB[512 / TPB];
#pragma unroll
    for (int s = 0; s < (BM * 4) / TPB; ++s) {
      int q = s * TPB + tid;
      int r = q >> 2;
      int cs = (q & 3) ^ ((r >> 1) & 3);
      stA[s] = *(const f16x8*)(A + (size_t)(rowBase + r) * K + kv + cs * 8);
    }
#pragma unroll
    for (int s = 0; s < 512 / TPB; ++s) {
      int q = s * TPB + tid;
      int r = q >> 2;
      int cs = (q & 3) ^ ((r >> 1) & 3);
      stB[s] = *(const f16x8*)(Bm + (size_t)(colBase + r) * K + kv + cs * 8);
    }
#pragma unroll
    for (int s = 0; s < (BM * 4) / TPB; ++s)
      *(f16x8*)&lA[(size_t)(s * TPB + tid) * 8] = stA[s];
#pragma unroll
    for (int s = 0; s < 512 / TPB; ++s)
      *(f16x8*)&lB[(size_t)(s * TPB + tid) * 8] = stB[s];
    __syncthreads();
    f16x8 aF[4], bF[4];
#pragma unroll
    for (int i = 0; i < 4; ++i) {
      int ra = wm * 64 + i * 16 + lrow;
      aF[i] = *(const f16x8*)&lA[(ra * 4 + (lk ^ ((ra >> 1) & 3))) * 8];
      int rb = wn * 64 + i * 16 + lrow;
      bF[i] = *(const f16x8*)&lB[(rb * 4 + (lk ^ ((rb >> 1) & 3))) * 8];
    }
#pragma unroll
    for (int i = 0; i < 4; ++i)
#pragma unroll
      for (int j = 0; j < 4; ++j)
        acc[i][j] = __builtin_amdgcn_mfma_f32_16x16x32_f16(aF[i], bF[j], acc[i][j], 0, 0, 0);
    __syncthreads();
  }
  // C/D layout: col = lane&15, row = (lane>>4)*4 + reg
#pragma unroll
  for (int i = 0; i < 4; ++i) {
    int row0 = rowBase + wm * 64 + i * 16 + lk * 4;
#pragma unroll
    for (int j = 0; j < 4; ++j) {
      int col = colBase + wn * 64 + j * 16 + lrow;
#pragma unroll
      for (int rr = 0; rr < 4; ++rr)
        C[(size_t)(row0 + rr) * Ncols + col] = (f16)acc[i][j][rr];
    }
  }
}

// ------------------- attention coefficients a_src / a_dst ------------------
__global__ __launch_bounds__(256) void attn_coef_kernel(
    const f16* __restrict__ xw, const float* __restrict__ attS,
    const float* __restrict__ attD, float* __restrict__ aS, float* __restrict__ aD,
    int NH, int H) {
  int wg = blockIdx.x * 4 + (threadIdx.x >> 6);
  int lane = threadIdx.x & 63;
  if (wg >= NH) return;
  int h = wg & (H - 1);
  const f16x2 v = *(const f16x2*)&xw[(size_t)wg * 128 + lane * 2];
  const float2 s2 = *(const float2*)&attS[h * 128 + lane * 2];
  const float2 d2 = *(const float2*)&attD[h * 128 + lane * 2];
  float ps = (float)v[0] * s2.x + (float)v[1] * s2.y;
  float pd = (float)v[0] * d2.x + (float)v[1] * d2.y;
#pragma unroll
  for (int off = 32; off; off >>= 1) {
    ps += __shfl_xor(ps, off);
    pd += __shfl_xor(pd, off);
  }
  if (lane == 0) { aS[wg] = ps; aD[wg] = pd; }
}

// -------------------- per-edge alpha precompute ----------------------------
// packed[h*EA + e] = (bitcast(src), exp(leakyrelu(aS[src,h]+aD[dst,h]))).
// grid: (ceil(EA/256), H). Softmax w/o max-subtraction (|e| <~ 10, f32 safe).
__global__ void edge_alpha_kernel(const int* __restrict__ csr,
                                  const int* __restrict__ dstOf,
                                  const float* __restrict__ aS,
                                  const float* __restrict__ aD,
                                  float2* __restrict__ packed, int EA, int H) {
  int e = blockIdx.x * 256 + threadIdx.x;
  if (e >= EA) return;
  int h = blockIdx.y;
  int s = csr[e], d = dstOf[e];
  float x = aS[s * H + h] + aD[d * H + h];
  x = (x > 0.f) ? x : 0.2f * x;
  packed[(size_t)h * EA + e] = make_float2(__int_as_float(s), __expf(x));
}

// --------------------- layer-1 aggregation (per dst) -----------------------
// block = 4 waves = 4 heads, one dst per block. Inner loop is pure
// (src,alpha) broadcast-load + row gather + FMA; 2 edges/iter (half=lane>>5),
// 8-pair unroll = 16 gathers in flight. Epilogue: elu(acc+b1) -> f16 A2.
__global__ __launch_bounds__(256) void agg1_kernel(
    const int* __restrict__ row_ptr, const float2* __restrict__ packed,
    const f16* __restrict__ xw, const float* __restrict__ bias,
    f16* __restrict__ A2, int EA) {
  const int dst = blockIdx.x;
  const int h = threadIdx.x >> 6, lane = threadIdx.x & 63;
  const int half = lane >> 5, lc = lane & 31;
  const int beg = row_ptr[dst], end = row_ptr[dst + 1];
  const float2* __restrict__ pk = packed + (size_t)h * EA;

  float den = 0.f;
  for (int i = beg + lane; i < end; i += 64) den += pk[i].y;
#pragma unroll
  for (int off = 32; off; off >>= 1) den += __shfl_xor(den, off);
  const float inv = 1.f / den;

  f32x4 acc = {0.f, 0.f, 0.f, 0.f};
  const f16* __restrict__ xrow = xw + h * 128 + lc * 4;
  const int deg = end - beg;
  const int Pfull = deg >> 1;  // complete pairs (both halves in range)
  int p = 0;
  for (; p + 8 <= Pfull; p += 8) {
    float a[8];
    int sj[8];
    f16x4 v[8];
#pragma unroll
    for (int k = 0; k < 8; ++k) {
      float2 pa = pk[beg + (p + k) * 2 + half];
      sj[k] = __float_as_int(pa.x);
      a[k] = pa.y * inv;
    }
#pragma unroll
    for (int k = 0; k < 8; ++k) v[k] = *(const f16x4*)&xrow[(size_t)sj[k] * 512];
#pragma unroll
    for (int k = 0; k < 8; ++k) {
      acc[0] = fmaf(a[k], (float)v[k][0], acc[0]);
      acc[1] = fmaf(a[k], (float)v[k][1], acc[1]);
      acc[2] = fmaf(a[k], (float)v[k][2], acc[2]);
      acc[3] = fmaf(a[k], (float)v[k][3], acc[3]);
    }
  }
  for (; p < Pfull; ++p) {
    float2 pa = pk[beg + p * 2 + half];
    int sj0 = __float_as_int(pa.x);
    float a0 = pa.y * inv;
    f16x4 v0 = *(const f16x4*)&xrow[(size_t)sj0 * 512];
    acc[0] = fmaf(a0, (float)v0[0], acc[0]);
    acc[1] = fmaf(a0, (float)v0[1], acc[1]);
    acc[2] = fmaf(a0, (float)v0[2], acc[2]);
    acc[3] = fmaf(a0, (float)v0[3], acc[3]);
  }
  if (deg & 1) {  // trailing odd edge: half 0 does it, half 1 adds zero
    float2 pa = pk[end - 1];
    int sj0 = (half == 0) ? __float_as_int(pa.x) : 0;
    float a0 = (half == 0) ? pa.y * inv : 0.f;
    f16x4 v0 = *(const f16x4*)&xrow[(size_t)sj0 * 512];
    acc[0] = fmaf(a0, (float)v0[0], acc[0]);
    acc[1] = fmaf(a0, (float)v0[1], acc[1]);
    acc[2] = fmaf(a0, (float)v0[2], acc[2]);
    acc[3] = fmaf(a0, (float)v0[3], acc[3]);
  }
#pragma unroll
  for (int k = 0; k < 4; ++k) acc[k] += __shfl_xor(acc[k], 32);
  if (half == 0) {
    const int c = h * 128 + lc * 4;
    f16x4 o;
#pragma unroll
    for (int k = 0; k < 4; ++k) {
      float vv = acc[k] + bias[c + k];
      vv = (vv > 0.f) ? vv : (__expf(vv) - 1.f);
      o[k] = (f16)vv;
    }
    *(f16x4*)&A2[(size_t)dst * 512 + c] = o;
  }
}

// ------------- layer-2 aggregation + ELU + fused classifier ----------------
// one wave per dst (H=1, C=128); block = 4 dst; same structure as agg1.
__global__ __launch_bounds__(256) void agg2_kernel(
    const int* __restrict__ row_ptr, const float2* __restrict__ pk,
    const f16* __restrict__ xw2, const float* __restrict__ b2,
    const float* __restrict__ Wc, const float* __restrict__ bc,
    float* __restrict__ out, int n) {
  const int dst = blockIdx.x * 4 + (threadIdx.x >> 6);
  const int lane = threadIdx.x & 63;
  const int half = lane >> 5, lc = lane & 31;
  if (dst >= n) return;
  const int beg = row_ptr[dst], end = row_ptr[dst + 1];

  float den = 0.f;
  for (int i = beg + lane; i < end; i += 64) den += pk[i].y;
#pragma unroll
  for (int off = 32; off; off >>= 1) den += __shfl_xor(den, off);
  const float inv = 1.f / den;

  f32x4 acc = {0.f, 0.f, 0.f, 0.f};
  const f16* __restrict__ xrow = xw2 + lc * 4;
  const int deg = end - beg;
  const int Pfull = deg >> 1;
  int p = 0;
  for (; p + 8 <= Pfull; p += 8) {
    float a[8];
    int sj[8];
    f16x4 v[8];
#pragma unroll
    for (int k = 0; k < 8; ++k) {
      float2 pa = pk[beg + (p + k) * 2 + half];
      sj[k] = __float_as_int(pa.x);
      a[k] = pa.y * inv;
    }
#pragma unroll
    for (int k = 0; k < 8; ++k) v[k] = *(const f16x4*)&xrow[(size_t)sj[k] * 128];
#pragma unroll
    for (int k = 0; k < 8; ++k) {
      acc[0] = fmaf(a[k], (float)v[k][0], acc[0]);
      acc[1] = fmaf(a[k], (float)v[k][1], acc[1]);
      acc[2] = fmaf(a[k], (float)v[k][2], acc[2]);
      acc[3] = fmaf(a[k], (float)v[k][3], acc[3]);
    }
  }
  for (; p < Pfull; ++p) {
    float2 pa = pk[beg + p * 2 + half];
    int sj0 = __float_as_int(pa.x);
    float a0 = pa.y * inv;
    f16x4 v0 = *(const f16x4*)&xrow[(size_t)sj0 * 128];
    acc[0] = fmaf(a0, (float)v0[0], acc[0]);
    acc[1] = fmaf(a0, (float)v0[1], acc[1]);
    acc[2] = fmaf(a0, (float)v0[2], acc[2]);
    acc[3] = fmaf(a0, (float)v0[3], acc[3]);
  }
  if (deg & 1) {
    float2 pa = pk[end - 1];
    int sj0 = (half == 0) ? __float_as_int(pa.x) : 0;
    float a0 = (half == 0) ? pa.y * inv : 0.f;
    f16x4 v0 = *(const f16x4*)&xrow[(size_t)sj0 * 128];
    acc[0] = fmaf(a0, (float)v0[0], acc[0]);
    acc[1] = fmaf(a0, (float)v0[1], acc[1]);
    acc[2] = fmaf(a0, (float)v0[2], acc[2]);
    acc[3] = fmaf(a0, (float)v0[3], acc[3]);
  }
#pragma unroll
  for (int k = 0; k < 4; ++k) acc[k] += __shfl_xor(acc[k], 32);
  // ELU + classifier: each lane holds 4 channels c = lc*4..lc*4+3
  const int c = lc * 4;
  float l0 = 0.f, l1 = 0.f;
#pragma unroll
  for (int k = 0; k < 4; ++k) {
    float vv = acc[k] + b2[c + k];
    vv = (vv > 0.f) ? vv : (__expf(vv) - 1.f);
    l0 = fmaf(vv, Wc[c + k], l0);
    l1 = fmaf(vv, Wc[128 + c + k], l1);
  }
#pragma unroll
  for (int off = 16; off; off >>= 1) {
    l0 += __shfl_xor(l0, off);
    l1 += __shfl_xor(l1, off);
  }
  if (lane == 0) {
    out[dst * 2] = l0 + bc[0];
    out[dst * 2 + 1] = l1 + bc[1];
  }
}

// ---------------------------------------------------------------------------

extern "C" void kernel_launch(void* const* d_in, const int* in_sizes, int n_in,
                              void* d_out, int out_size, void* d_ws, size_t ws_size,
                              hipStream_t stream) {
  const float* x     = (const float*)d_in[0];
  const int*   ei    = (const int*)d_in[1];
  const float* W1    = (const float*)d_in[2];
  const float* att1s = (const float*)d_in[3];
  const float* att1d = (const float*)d_in[4];
  const float* b1    = (const float*)d_in[5];
  const float* W2    = (const float*)d_in[6];
  const float* att2s = (const float*)d_in[7];
  const float* att2d = (const float*)d_in[8];
  const float* b2    = (const float*)d_in[9];
  const float* Wc    = (const float*)d_in[10];
  const float* bc    = (const float*)d_in[11];
  float* out = (float*)d_out;

  const int N = in_sizes[0] / 256;
  const int E = in_sizes[1] / 2;
  const int EA = E + N;
  const int Mpad = (N + 127) & ~127;
  const int NB = (N + 255) / 256;
  const int EB = (EA + 255) / 256;

  char* base = (char*)d_ws;
  size_t off = 0;
  auto alloc = [&](size_t bytes) -> char* {
    char* p = base + off;
    off = (off + bytes + 255) & ~(size_t)255;
    return p;
  };
  f16* A1f  = (f16*)alloc((size_t)Mpad * 256 * sizeof(f16));   // x in f16
  f16* B1f  = (f16*)alloc((size_t)512 * 256 * sizeof(f16));    // W1 f16
  f16* xw1h = (f16*)alloc((size_t)Mpad * 512 * sizeof(f16));   // layer1 pre-agg
  f16* A2   = (f16*)alloc((size_t)Mpad * 512 * sizeof(f16));   // h = elu(agg1)
  f16* B2f  = (f16*)alloc((size_t)128 * 512 * sizeof(f16));    // W2 f16
  f16* xw2h = (f16*)alloc((size_t)Mpad * 128 * sizeof(f16));   // layer2 pre-agg
  float* aS1 = (float*)alloc((size_t)N * 4 * sizeof(float));
  float* aD1 = (float*)alloc((size_t)N * 4 * sizeof(float));
  float* aS2 = (float*)alloc((size_t)N * sizeof(float));
  float* aD2 = (float*)alloc((size_t)N * sizeof(float));
  float2* pk1 = (float2*)alloc((size_t)4 * EA * sizeof(float2));  // (src,alpha) per head
  float2* pk2 = (float2*)alloc((size_t)EA * sizeof(float2));
  int* deg     = (int*)alloc((size_t)N * sizeof(int));
  int* row_ptr = (int*)alloc((size_t)(N + 1) * sizeof(int));
  int* cursor  = (int*)alloc((size_t)N * sizeof(int));
  int* csr     = (int*)alloc((size_t)EA * sizeof(int));
  int* dstOf   = (int*)alloc((size_t)EA * sizeof(int));
  int* tmp     = (int*)alloc((size_t)N * sizeof(int));
  int* bsum    = (int*)alloc((size_t)NB * sizeof(int));
  int* boff    = (int*)alloc((size_t)NB * sizeof(int));
  int* flag    = (int*)alloc(256);
  (void)n_in; (void)out_size; (void)ws_size;

  hipMemsetAsync(deg, 0, (size_t)N * sizeof(int), stream);
  if (Mpad > N)  // zero A2 pad rows so GEMM2 pad outputs stay finite
    hipMemsetAsync(A2 + (size_t)N * 512, 0, (size_t)(Mpad - N) * 512 * sizeof(f16), stream);

  detect_i64_kernel<<<1, 64, 0, stream>>>(ei, flag);
  hist_kernel<<<EB, 256, 0, stream>>>(ei, E, N, flag, deg);
  scan1_kernel<<<NB, 256, 0, stream>>>(deg, tmp, bsum, N);
  scan2_kernel<<<1, 256, 0, stream>>>(bsum, boff, NB);
  scan3_kernel<<<NB, 256, 0, stream>>>(deg, tmp, boff, row_ptr, cursor, N);
  scatter_kernel<<<EB, 256, 0, stream>>>(ei, E, N, flag, cursor, csr, dstOf);

  cvt_f16_kernel<<<(Mpad * 64 + 255) / 256, 256, 0, stream>>>(x, A1f, N, Mpad, 256, 6);
  cvt_f16_kernel<<<(512 * 64 + 255) / 256, 256, 0, stream>>>(W1, B1f, 512, 512, 256, 6);
  cvt_f16_kernel<<<(128 * 128 + 255) / 256, 256, 0, stream>>>(W2, B2f, 128, 128, 512, 7);

  dim3 g1(4, Mpad / 128);
  gemm_f16_kernel<128, 256><<<g1, 256, 0, stream>>>(A1f, B1f, xw1h, 256, 512);
  attn_coef_kernel<<<N, 256, 0, stream>>>(xw1h, att1s, att1d, aS1, aD1, N * 4, 4);
  edge_alpha_kernel<<<dim3(EB, 4), 256, 0, stream>>>(csr, dstOf, aS1, aD1, pk1, EA, 4);
  agg1_kernel<<<N, 256, 0, stream>>>(row_ptr, pk1, xw1h, b1, A2, EA);

  dim3 g2(1, Mpad / 64);
  gemm_f16_kernel<64, 128><<<g2, 128, 0, stream>>>(A2, B2f, xw2h, 512, 128);
  attn_coef_kernel<<<(N + 3) / 4, 256, 0, stream>>>(xw2h, att2s, att2d, aS2, aD2, N, 1);
  edge_alpha_kernel<<<dim3(EB, 1), 256, 0, stream>>>(csr, dstOf, aS2, aD2, pk2, EA, 1);
  agg2_kernel<<<(N + 3) / 4, 256, 0, stream>>>(row_ptr, pk2, xw2h, b2, Wc, bc, out, N);
}

// Round 6
// 489.224 us; speedup vs baseline: 1.1044x; 1.1044x over previous
//
#include <hip/hip_runtime.h>
#include <stdint.h>

// ---------------------------------------------------------------------------
// GAT bot detector, 2-layer, N=50000 E=800000 IN=256 HID=128 HEADS=4.
// Round 6: edge-alpha precompute (r5) + LDS/register broadcast (r4 lesson:
// keep metadata off the vmcnt path). agg1 = wave-per-dst full-row f16x8
// gathers; agg2 = 2-edge split. Normalization deferred to the epilogue
// (out = (sum alpha*v)/den) so den never blocks the main loop.
// Sync-staged GEMMs kept (global_load_lds proved racy in r2).
// ---------------------------------------------------------------------------

typedef _Float16 f16;
typedef f16 f16x8 __attribute__((ext_vector_type(8)));
typedef f16 f16x4 __attribute__((ext_vector_type(4)));
typedef f16 f16x2 __attribute__((ext_vector_type(2)));
typedef float f32x4 __attribute__((ext_vector_type(4)));

// --------------------------- CSR construction ------------------------------

__global__ void detect_i64_kernel(const int* __restrict__ ei, int* __restrict__ flag) {
  if (threadIdx.x == 0 && blockIdx.x == 0) {
    int nz = 0;
    for (int i = 0; i < 256; ++i) nz |= ei[2 * i + 1];
    *flag = (nz == 0) ? 1 : 0;
  }
}

__global__ void hist_kernel(const int* __restrict__ ei, int E, int N,
                            const int* __restrict__ flagp, int* __restrict__ deg) {
  int idx = blockIdx.x * blockDim.x + threadIdx.x;
  int EA = E + N;
  if (idx >= EA) return;
  int dst;
  if (idx < E) {
    dst = (*flagp) ? ei[2 * ((size_t)E + idx)] : ei[(size_t)E + idx];
  } else {
    dst = idx - E;  // self loop
  }
  if ((unsigned)dst >= (unsigned)N) return;
  atomicAdd(&deg[dst], 1);
}

// 3-phase scan: per-block inclusive -> block-sums scan -> fixup.
__global__ __launch_bounds__(256) void scan1_kernel(const int* __restrict__ deg,
                                                    int* __restrict__ tmp,
                                                    int* __restrict__ bsum, int n) {
  __shared__ int sd[256];
  const int t = threadIdx.x;
  const int i = blockIdx.x * 256 + t;
  int x = (i < n) ? deg[i] : 0;
  sd[t] = x;
  __syncthreads();
  for (int off = 1; off < 256; off <<= 1) {
    int v = (t >= off) ? sd[t - off] : 0;
    __syncthreads();
    sd[t] += v;
    __syncthreads();
  }
  if (i < n) tmp[i] = sd[t];
  if (t == 255) bsum[blockIdx.x] = sd[255];
}

__global__ __launch_bounds__(256) void scan2_kernel(const int* __restrict__ bsum,
                                                    int* __restrict__ boff, int nb) {
  __shared__ int sd[256];
  const int t = threadIdx.x;
  int x = (t < nb) ? bsum[t] : 0;
  sd[t] = x;
  __syncthreads();
  for (int off = 1; off < 256; off <<= 1) {
    int v = (t >= off) ? sd[t - off] : 0;
    __syncthreads();
    sd[t] += v;
    __syncthreads();
  }
  if (t < nb) boff[t] = sd[t] - x;  // exclusive
}

__global__ void scan3_kernel(const int* __restrict__ deg, const int* __restrict__ tmp,
                             const int* __restrict__ boff, int* __restrict__ row_ptr,
                             int* __restrict__ cursor, int n) {
  int i = blockIdx.x * 256 + threadIdx.x;
  if (i >= n) return;
  int g = tmp[i] + boff[i >> 8];
  row_ptr[i + 1] = g;
  cursor[i] = g - deg[i];
  if (i == 0) row_ptr[0] = 0;
}

__global__ void scatter_kernel(const int* __restrict__ ei, int E, int N,
                               const int* __restrict__ flagp,
                               int* __restrict__ cursor, int* __restrict__ csr,
                               int* __restrict__ dstOf) {
  int idx = blockIdx.x * blockDim.x + threadIdx.x;
  int EA = E + N;
  if (idx >= EA) return;
  int src, dst;
  if (idx < E) {
    if (*flagp) { src = ei[2 * (size_t)idx]; dst = ei[2 * ((size_t)E + idx)]; }
    else        { src = ei[(size_t)idx];     dst = ei[(size_t)E + idx]; }
  } else {
    src = dst = idx - E;
  }
  if ((unsigned)dst >= (unsigned)N || (unsigned)src >= (unsigned)N) return;
  int pos = atomicAdd(&cursor[dst], 1);
  csr[pos] = src;
  dstOf[pos] = dst;
}

// --------------------------- f32 -> f16 convert ----------------------------
__global__ void cvt_f16_kernel(const float* __restrict__ src, f16* __restrict__ dst,
                               int srcRows, int dstRows, int cols, int gshift) {
  int idx = blockIdx.x * blockDim.x + threadIdx.x;
  int total = dstRows << gshift;
  if (idx >= total) return;
  int row = idx >> gshift;
  int col = (idx & ((1 << gshift) - 1)) * 4;
  float4 v = make_float4(0.f, 0.f, 0.f, 0.f);
  if (row < srcRows) v = *(const float4*)&src[(size_t)row * cols + col];
  f16x4 o = {(f16)v.x, (f16)v.y, (f16)v.z, (f16)v.w};
  *(f16x4*)&dst[(size_t)row * cols + col] = o;
}

// ------------------------------ f16 GEMM -----------------------------------
// C[M,Ncols] = A * B^T, sync staging (global vec load -> ds_write), XOR
// swizzle on 16B chunks to keep ds_read_b128 conflict-free.
template <int BM, int TPB>
__global__ __launch_bounds__(TPB) void gemm_f16_kernel(
    const f16* __restrict__ A, const f16* __restrict__ Bm, f16* __restrict__ C,
    int K, int Ncols) {
  __shared__ f16 lA[BM * 32];
  __shared__ f16 lB[128 * 32];
  const int tid = threadIdx.x;
  const int w = tid >> 6, lane = tid & 63;
  const int wm = w >> 1, wn = w & 1;
  const int rowBase = blockIdx.y * BM;
  const int colBase = blockIdx.x * 128;
  const int lrow = lane & 15, lk = lane >> 4;
  f32x4 acc[4][4];
#pragma unroll
  for (int i = 0; i < 4; ++i)
#pragma unroll
    for (int j = 0; j < 4; ++j) acc[i][j] = (f32x4){0.f, 0.f, 0.f, 0.f};

  for (int kv = 0; kv < K; kv += 32) {
    f16x8 stA[(BM * 4) / TPB], stB[512 / TPB];
#pragma unroll
    for (int s = 0; s < (BM * 4) / TPB; ++s) {
      int q = s * TPB + tid;
      int r = q >> 2;
      int cs = (q & 3) ^ ((r >> 1) & 3);
      stA[s] = *(const f16x8*)(A + (size_t)(rowBase + r) * K + kv + cs * 8);
    }
#pragma unroll
    for (int s = 0; s < 512 / TPB; ++s) {
      int q = s * TPB + tid;
      int r = q >> 2;
      int cs = (q & 3) ^ ((r >> 1) & 3);
      stB[s] = *(const f16x8*)(Bm + (size_t)(colBase + r) * K + kv + cs * 8);
    }
#pragma unroll
    for (int s = 0; s < (BM * 4) / TPB; ++s)
      *(f16x8*)&lA[(size_t)(s * TPB + tid) * 8] = stA[s];
#pragma unroll
    for (int s = 0; s < 512 / TPB; ++s)
      *(f16x8*)&lB[(size_t)(s * TPB + tid) * 8] = stB[s];
    __syncthreads();
    f16x8 aF[4], bF[4];
#pragma unroll
    for (int i = 0; i < 4; ++i) {
      int ra = wm * 64 + i * 16 + lrow;
      aF[i] = *(const f16x8*)&lA[(ra * 4 + (lk ^ ((ra >> 1) & 3))) * 8];
      int rb = wn * 64 + i * 16 + lrow;
      bF[i] = *(const f16x8*)&lB[(rb * 4 + (lk ^ ((rb >> 1) & 3))) * 8];
    }
#pragma unroll
    for (int i = 0; i < 4; ++i)
#pragma unroll
      for (int j = 0; j < 4; ++j)
        acc[i][j] = __builtin_amdgcn_mfma_f32_16x16x32_f16(aF[i], bF[j], acc[i][j], 0, 0, 0);
    __syncthreads();
  }
  // C/D layout: col = lane&15, row = (lane>>4)*4 + reg
#pragma unroll
  for (int i = 0; i < 4; ++i) {
    int row0 = rowBase + wm * 64 + i * 16 + lk * 4;
#pragma unroll
    for (int j = 0; j < 4; ++j) {
      int col = colBase + wn * 64 + j * 16 + lrow;
#pragma unroll
      for (int rr = 0; rr < 4; ++rr)
        C[(size_t)(row0 + rr) * Ncols + col] = (f16)acc[i][j][rr];
    }
  }
}

// ------------------- attention coefficients a_src / a_dst ------------------
__global__ __launch_bounds__(256) void attn_coef_kernel(
    const f16* __restrict__ xw, const float* __restrict__ attS,
    const float* __restrict__ attD, float* __restrict__ aS, float* __restrict__ aD,
    int NH, int H) {
  int wg = blockIdx.x * 4 + (threadIdx.x >> 6);
  int lane = threadIdx.x & 63;
  if (wg >= NH) return;
  int h = wg & (H - 1);
  const f16x2 v = *(const f16x2*)&xw[(size_t)wg * 128 + lane * 2];
  const float2 s2 = *(const float2*)&attS[h * 128 + lane * 2];
  const float2 d2 = *(const float2*)&attD[h * 128 + lane * 2];
  float ps = (float)v[0] * s2.x + (float)v[1] * s2.y;
  float pd = (float)v[0] * d2.x + (float)v[1] * d2.y;
#pragma unroll
  for (int off = 32; off; off >>= 1) {
    ps += __shfl_xor(ps, off);
    pd += __shfl_xor(pd, off);
  }
  if (lane == 0) { aS[wg] = ps; aD[wg] = pd; }
}

// -------------------- per-edge alpha precompute ----------------------------
// Layer 1: alpha4[e] = exp(leakyrelu(aS[src,:] + aD[dst,:])) for 4 heads.
// Softmax w/o max-subtraction (|e| <~ 10, f32-safe); normalize in agg epilogue.
__global__ void edge_alpha1_kernel(const int* __restrict__ csr,
                                   const int* __restrict__ dstOf,
                                   const float* __restrict__ aS,
                                   const float* __restrict__ aD,
                                   float4* __restrict__ alpha4, int EA) {
  int e = blockIdx.x * 256 + threadIdx.x;
  if (e >= EA) return;
  int s = csr[e], d = dstOf[e];
  float4 as4 = *(const float4*)&aS[(size_t)s * 4];
  float4 ad4 = *(const float4*)&aD[(size_t)d * 4];
  float4 o;
  float x0 = as4.x + ad4.x; x0 = (x0 > 0.f) ? x0 : 0.2f * x0; o.x = __expf(x0);
  float x1 = as4.y + ad4.y; x1 = (x1 > 0.f) ? x1 : 0.2f * x1; o.y = __expf(x1);
  float x2 = as4.z + ad4.z; x2 = (x2 > 0.f) ? x2 : 0.2f * x2; o.z = __expf(x2);
  float x3 = as4.w + ad4.w; x3 = (x3 > 0.f) ? x3 : 0.2f * x3; o.w = __expf(x3);
  alpha4[e] = o;
}

// Layer 2: pk2[e] = (bitcast(src), alpha).
__global__ void edge_alpha2_kernel(const int* __restrict__ csr,
                                   const int* __restrict__ dstOf,
                                   const float* __restrict__ aS,
                                   const float* __restrict__ aD,
                                   float2* __restrict__ pk, int EA) {
  int e = blockIdx.x * 256 + threadIdx.x;
  if (e >= EA) return;
  int s = csr[e], d = dstOf[e];
  float x = aS[s] + aD[d];
  x = (x > 0.f) ? x : 0.2f * x;
  pk[e] = make_float2(__int_as_float(s), __expf(x));
}

// --------------------- layer-1 aggregation (per dst) -----------------------
// One wave per dst; lane owns 8 contiguous channels (f16x8, 16 B gather).
// Per 64-edge batch: stage (src, alpha4) into wave-private LDS (coalesced),
// s_waitcnt lgkmcnt(0) for wave-internal visibility (no barrier: waves have
// divergent trip counts), then per-edge LDS broadcast + row gather + FMA.
// den accumulated during staging; normalization + ELU + bias in epilogue.
__global__ __launch_bounds__(256) void agg1_kernel(
    const int* __restrict__ row_ptr, const int* __restrict__ csr,
    const float4* __restrict__ alpha4, const f16* __restrict__ xw,
    const float* __restrict__ bias, f16* __restrict__ A2, int n) {
  __shared__ float4 lal[4][64];
  __shared__ int lsrc[4][64];
  const int wv = threadIdx.x >> 6, lane = threadIdx.x & 63;
  const int dst = blockIdx.x * 4 + wv;
  if (dst >= n) return;
  const int beg = row_ptr[dst], end = row_ptr[dst + 1];
  const int hh = lane >> 4;  // head of this lane's 8 channels (lane*8/128)
  f32x4 den4 = {0.f, 0.f, 0.f, 0.f};
  float acc[8] = {0.f, 0.f, 0.f, 0.f, 0.f, 0.f, 0.f, 0.f};
  const f16* __restrict__ xcol = xw + lane * 8;
  const float* __restrict__ lalf = (const float*)&lal[wv][0];

  for (int base = beg; base < end; base += 64) {
    int i = base + lane;
    int s = 0;
    float4 a4 = make_float4(0.f, 0.f, 0.f, 0.f);
    if (i < end) { s = csr[i]; a4 = alpha4[i]; }
    den4[0] += a4.x; den4[1] += a4.y; den4[2] += a4.z; den4[3] += a4.w;
    lsrc[wv][lane] = s;
    lal[wv][lane] = a4;
    asm volatile("s_waitcnt lgkmcnt(0)" ::: "memory");
    const int m = min(64, end - base);
    int j = 0;
    for (; j + 4 <= m; j += 4) {
      int sj[4];
      float aj[4];
      f16x8 v[4];
#pragma unroll
      for (int k = 0; k < 4; ++k) {
        sj[k] = lsrc[wv][j + k];
        aj[k] = lalf[(j + k) * 4 + hh];
      }
#pragma unroll
      for (int k = 0; k < 4; ++k) v[k] = *(const f16x8*)&xcol[(size_t)sj[k] * 512];
#pragma unroll
      for (int k = 0; k < 4; ++k)
#pragma unroll
        for (int q = 0; q < 8; ++q) acc[q] = fmaf(aj[k], (float)v[k][q], acc[q]);
    }
    for (; j < m; ++j) {
      int sj = lsrc[wv][j];
      float aj = lalf[j * 4 + hh];
      f16x8 v = *(const f16x8*)&xcol[(size_t)sj * 512];
#pragma unroll
      for (int q = 0; q < 8; ++q) acc[q] = fmaf(aj, (float)v[q], acc[q]);
    }
  }
  // reduce den4 across wave, pick this lane's head, normalize in epilogue
#pragma unroll
  for (int off = 32; off; off >>= 1) {
#pragma unroll
    for (int k = 0; k < 4; ++k) den4[k] += __shfl_xor(den4[k], off);
  }
  float dh = (hh == 0) ? den4[0] : (hh == 1) ? den4[1] : (hh == 2) ? den4[2] : den4[3];
  const float inv = 1.f / dh;
  const int c = lane * 8;
  const float4 b0 = *(const float4*)&bias[c];
  const float4 b1 = *(const float4*)&bias[c + 4];
  const float bb[8] = {b0.x, b0.y, b0.z, b0.w, b1.x, b1.y, b1.z, b1.w};
  f16x8 o;
#pragma unroll
  for (int q = 0; q < 8; ++q) {
    float vv = acc[q] * inv + bb[q];
    vv = (vv > 0.f) ? vv : (__expf(vv) - 1.f);
    o[q] = (f16)vv;
  }
  *(f16x8*)&A2[(size_t)dst * 512 + c] = o;
}

// ------------- layer-2 aggregation + ELU + fused classifier ----------------
// One wave per dst (C=128): 2 edges/iter (half=lane>>5, 32 lanes x f16x4).
// (src,alpha) staged to wave-private LDS as float2; normalize at the end.
__global__ __launch_bounds__(256) void agg2_kernel(
    const int* __restrict__ row_ptr, const float2* __restrict__ pk,
    const f16* __restrict__ xw2, const float* __restrict__ b2,
    const float* __restrict__ Wc, const float* __restrict__ bc,
    float* __restrict__ out, int n) {
  __shared__ float2 led[4][64];
  const int wv = threadIdx.x >> 6, lane = threadIdx.x & 63;
  const int dst = blockIdx.x * 4 + wv;
  if (dst >= n) return;
  const int beg = row_ptr[dst], end = row_ptr[dst + 1];
  const int half = lane >> 5, lc = lane & 31;
  float den = 0.f;
  float acc[4] = {0.f, 0.f, 0.f, 0.f};
  const f16* __restrict__ xrow = xw2 + lc * 4;

  for (int base = beg; base < end; base += 64) {
    int i = base + lane;
    float2 pa = make_float2(__int_as_float(0), 0.f);
    if (i < end) pa = pk[i];
    den += pa.y;
    led[wv][lane] = pa;
    asm volatile("s_waitcnt lgkmcnt(0)" ::: "memory");
    const int m = min(64, end - base);
    const int pairs = (m + 1) >> 1;
    int p = 0;
    for (; p + 8 <= pairs; p += 8) {
      int sj[8];
      float aj[8];
      f16x4 v[8];
#pragma unroll
      for (int k = 0; k < 8; ++k) {
        float2 q = led[wv][(p + k) * 2 + half];
        sj[k] = __float_as_int(q.x);
        aj[k] = q.y;
      }
#pragma unroll
      for (int k = 0; k < 8; ++k) v[k] = *(const f16x4*)&xrow[(size_t)sj[k] * 128];
#pragma unroll
      for (int k = 0; k < 8; ++k) {
        acc[0] = fmaf(aj[k], (float)v[k][0], acc[0]);
        acc[1] = fmaf(aj[k], (float)v[k][1], acc[1]);
        acc[2] = fmaf(aj[k], (float)v[k][2], acc[2]);
        acc[3] = fmaf(aj[k], (float)v[k][3], acc[3]);
      }
    }
    for (; p < pairs; ++p) {
      float2 q = led[wv][p * 2 + half];  // odd tail slot was staged as alpha=0
      int sj = __float_as_int(q.x);
      float aj = q.y;
      f16x4 v = *(const f16x4*)&xrow[(size_t)sj * 128];
      acc[0] = fmaf(aj, (float)v[0], acc[0]);
      acc[1] = fmaf(aj, (float)v[1], acc[1]);
      acc[2] = fmaf(aj, (float)v[2], acc[2]);
      acc[3] = fmaf(aj, (float)v[3], acc[3]);
    }
  }
#pragma unroll
  for (int off = 32; off; off >>= 1) den += __shfl_xor(den, off);
  const float inv = 1.f / den;
#pragma unroll
  for (int k = 0; k < 4; ++k) acc[k] += __shfl_xor(acc[k], 32);
  // ELU + classifier: lane owns channels c = lc*4..lc*4+3 (both halves dup)
  const int c = lc * 4;
  const float4 bb = *(const float4*)&b2[c];
  const float4 w0 = *(const float4*)&Wc[c];
  const float4 w1 = *(const float4*)&Wc[128 + c];
  const float bv[4] = {bb.x, bb.y, bb.z, bb.w};
  const float w0v[4] = {w0.x, w0.y, w0.z, w0.w};
  const float w1v[4] = {w1.x, w1.y, w1.z, w1.w};
  float l0 = 0.f, l1 = 0.f;
#pragma unroll
  for (int k = 0; k < 4; ++k) {
    float vv = acc[k] * inv + bv[k];
    vv = (vv > 0.f) ? vv : (__expf(vv) - 1.f);
    l0 = fmaf(vv, w0v[k], l0);
    l1 = fmaf(vv, w1v[k], l1);
  }
#pragma unroll
  for (int off = 16; off; off >>= 1) {
    l0 += __shfl_xor(l0, off);
    l1 += __shfl_xor(l1, off);
  }
  if (lane == 0) {
    out[dst * 2] = l0 + bc[0];
    out[dst * 2 + 1] = l1 + bc[1];
  }
}

// ---------------------------------------------------------------------------

extern "C" void kernel_launch(void* const* d_in, const int* in_sizes, int n_in,
                              void* d_out, int out_size, void* d_ws, size_t ws_size,
                              hipStream_t stream) {
  const float* x     = (const float*)d_in[0];
  const int*   ei    = (const int*)d_in[1];
  const float* W1    = (const float*)d_in[2];
  const float* att1s = (const float*)d_in[3];
  const float* att1d = (const float*)d_in[4];
  const float* b1    = (const float*)d_in[5];
  const float* W2    = (const float*)d_in[6];
  const float* att2s = (const float*)d_in[7];
  const float* att2d = (const float*)d_in[8];
  const float* b2    = (const float*)d_in[9];
  const float* Wc    = (const float*)d_in[10];
  const float* bc    = (const float*)d_in[11];
  float* out = (float*)d_out;

  const int N = in_sizes[0] / 256;
  const int E = in_sizes[1] / 2;
  const int EA = E + N;
  const int Mpad = (N + 127) & ~127;
  const int NB = (N + 255) / 256;
  const int EB = (EA + 255) / 256;

  char* base = (char*)d_ws;
  size_t off = 0;
  auto alloc = [&](size_t bytes) -> char* {
    char* p = base + off;
    off = (off + bytes + 255) & ~(size_t)255;
    return p;
  };
  f16* A1f  = (f16*)alloc((size_t)Mpad * 256 * sizeof(f16));   // x in f16
  f16* B1f  = (f16*)alloc((size_t)512 * 256 * sizeof(f16));    // W1 f16
  f16* xw1h = (f16*)alloc((size_t)Mpad * 512 * sizeof(f16));   // layer1 pre-agg
  f16* A2   = (f16*)alloc((size_t)Mpad * 512 * sizeof(f16));   // h = elu(agg1)
  f16* B2f  = (f16*)alloc((size_t)128 * 512 * sizeof(f16));    // W2 f16
  f16* xw2h = (f16*)alloc((size_t)Mpad * 128 * sizeof(f16));   // layer2 pre-agg
  float* aS1 = (float*)alloc((size_t)N * 4 * sizeof(float));
  float* aD1 = (float*)alloc((size_t)N * 4 * sizeof(float));
  float* aS2 = (float*)alloc((size_t)N * sizeof(float));
  float* aD2 = (float*)alloc((size_t)N * sizeof(float));
  float4* alpha4 = (float4*)alloc((size_t)EA * sizeof(float4));  // layer1 alphas
  float2* pk2    = (float2*)alloc((size_t)EA * sizeof(float2));  // layer2 (src,alpha)
  int* deg     = (int*)alloc((size_t)N * sizeof(int));
  int* row_ptr = (int*)alloc((size_t)(N + 1) * sizeof(int));
  int* cursor  = (int*)alloc((size_t)N * sizeof(int));
  int* csr     = (int*)alloc((size_t)EA * sizeof(int));
  int* dstOf   = (int*)alloc((size_t)EA * sizeof(int));
  int* tmp     = (int*)alloc((size_t)N * sizeof(int));
  int* bsum    = (int*)alloc((size_t)NB * sizeof(int));
  int* boff    = (int*)alloc((size_t)NB * sizeof(int));
  int* flag    = (int*)alloc(256);
  (void)n_in; (void)out_size; (void)ws_size;

  hipMemsetAsync(deg, 0, (size_t)N * sizeof(int), stream);
  if (Mpad > N)  // zero A2 pad rows so GEMM2 pad outputs stay finite
    hipMemsetAsync(A2 + (size_t)N * 512, 0, (size_t)(Mpad - N) * 512 * sizeof(f16), stream);

  detect_i64_kernel<<<1, 64, 0, stream>>>(ei, flag);
  hist_kernel<<<EB, 256, 0, stream>>>(ei, E, N, flag, deg);
  scan1_kernel<<<NB, 256, 0, stream>>>(deg, tmp, bsum, N);
  scan2_kernel<<<1, 256, 0, stream>>>(bsum, boff, NB);
  scan3_kernel<<<NB, 256, 0, stream>>>(deg, tmp, boff, row_ptr, cursor, N);
  scatter_kernel<<<EB, 256, 0, stream>>>(ei, E, N, flag, cursor, csr, dstOf);

  cvt_f16_kernel<<<(Mpad * 64 + 255) / 256, 256, 0, stream>>>(x, A1f, N, Mpad, 256, 6);
  cvt_f16_kernel<<<(512 * 64 + 255) / 256, 256, 0, stream>>>(W1, B1f, 512, 512, 256, 6);
  cvt_f16_kernel<<<(128 * 128 + 255) / 256, 256, 0, stream>>>(W2, B2f, 128, 128, 512, 7);

  dim3 g1(4, Mpad / 128);
  gemm_f16_kernel<128, 256><<<g1, 256, 0, stream>>>(A1f, B1f, xw1h, 256, 512);
  attn_coef_kernel<<<N, 256, 0, stream>>>(xw1h, att1s, att1d, aS1, aD1, N * 4, 4);
  edge_alpha1_kernel<<<EB, 256, 0, stream>>>(csr, dstOf, aS1, aD1, alpha4, EA);
  agg1_kernel<<<(N + 3) / 4, 256, 0, stream>>>(row_ptr, csr, alpha4, xw1h, b1, A2, N);

  dim3 g2(1, Mpad / 64);
  gemm_f16_kernel<64, 128><<<g2, 128, 0, stream>>>(A2, B2f, xw2h, 512, 128);
  attn_coef_kernel<<<(N + 3) / 4, 256, 0, stream>>>(xw2h, att2s, att2d, aS2, aD2, N, 1);
  edge_alpha2_kernel<<<EB, 256, 0, stream>>>(csr, dstOf, aS2, aD2, pk2, EA);
  agg2_kernel<<<(N + 3) / 4, 256, 0, stream>>>(row_ptr, pk2, xw2h, b2, Wc, bc, out, N);
}

// Round 7
// 463.414 us; speedup vs baseline: 1.1659x; 1.0557x over previous
//
#include <hip/hip_runtime.h>
#include <stdint.h>

// ---------------------------------------------------------------------------
// GAT bot detector, 2-layer, N=50000 E=800000 IN=256 HID=128 HEADS=4.
// Round 7: alpha fused into agg staging (aS table is L2-resident; dependent
// gather sits on the once-per-row staging path, not per-edge), branch-free
// 8-deep unroll via alpha=0 padding, x->f16 conversion fused into GEMM1
// staging. Sync-staged GEMMs kept (global_load_lds proved racy in r2).
// ---------------------------------------------------------------------------

typedef _Float16 f16;
typedef f16 f16x8 __attribute__((ext_vector_type(8)));
typedef f16 f16x4 __attribute__((ext_vector_type(4)));
typedef f16 f16x2 __attribute__((ext_vector_type(2)));
typedef float f32x4 __attribute__((ext_vector_type(4)));

// --------------------------- CSR construction ------------------------------

__global__ void detect_i64_kernel(const int* __restrict__ ei, int* __restrict__ flag) {
  if (threadIdx.x == 0 && blockIdx.x == 0) {
    int nz = 0;
    for (int i = 0; i < 256; ++i) nz |= ei[2 * i + 1];
    *flag = (nz == 0) ? 1 : 0;
  }
}

__global__ void hist_kernel(const int* __restrict__ ei, int E, int N,
                            const int* __restrict__ flagp, int* __restrict__ deg) {
  int idx = blockIdx.x * blockDim.x + threadIdx.x;
  int EA = E + N;
  if (idx >= EA) return;
  int dst;
  if (idx < E) {
    dst = (*flagp) ? ei[2 * ((size_t)E + idx)] : ei[(size_t)E + idx];
  } else {
    dst = idx - E;  // self loop
  }
  if ((unsigned)dst >= (unsigned)N) return;
  atomicAdd(&deg[dst], 1);
}

// 3-phase scan: per-block inclusive -> block-sums scan -> fixup.
__global__ __launch_bounds__(256) void scan1_kernel(const int* __restrict__ deg,
                                                    int* __restrict__ tmp,
                                                    int* __restrict__ bsum, int n) {
  __shared__ int sd[256];
  const int t = threadIdx.x;
  const int i = blockIdx.x * 256 + t;
  int x = (i < n) ? deg[i] : 0;
  sd[t] = x;
  __syncthreads();
  for (int off = 1; off < 256; off <<= 1) {
    int v = (t >= off) ? sd[t - off] : 0;
    __syncthreads();
    sd[t] += v;
    __syncthreads();
  }
  if (i < n) tmp[i] = sd[t];
  if (t == 255) bsum[blockIdx.x] = sd[255];
}

__global__ __launch_bounds__(256) void scan2_kernel(const int* __restrict__ bsum,
                                                    int* __restrict__ boff, int nb) {
  __shared__ int sd[256];
  const int t = threadIdx.x;
  int x = (t < nb) ? bsum[t] : 0;
  sd[t] = x;
  __syncthreads();
  for (int off = 1; off < 256; off <<= 1) {
    int v = (t >= off) ? sd[t - off] : 0;
    __syncthreads();
    sd[t] += v;
    __syncthreads();
  }
  if (t < nb) boff[t] = sd[t] - x;  // exclusive
}

__global__ void scan3_kernel(const int* __restrict__ deg, const int* __restrict__ tmp,
                             const int* __restrict__ boff, int* __restrict__ row_ptr,
                             int* __restrict__ cursor, int n) {
  int i = blockIdx.x * 256 + threadIdx.x;
  if (i >= n) return;
  int g = tmp[i] + boff[i >> 8];
  row_ptr[i + 1] = g;
  cursor[i] = g - deg[i];
  if (i == 0) row_ptr[0] = 0;
}

__global__ void scatter_kernel(const int* __restrict__ ei, int E, int N,
                               const int* __restrict__ flagp,
                               int* __restrict__ cursor, int* __restrict__ csr) {
  int idx = blockIdx.x * blockDim.x + threadIdx.x;
  int EA = E + N;
  if (idx >= EA) return;
  int src, dst;
  if (idx < E) {
    if (*flagp) { src = ei[2 * (size_t)idx]; dst = ei[2 * ((size_t)E + idx)]; }
    else        { src = ei[(size_t)idx];     dst = ei[(size_t)E + idx]; }
  } else {
    src = dst = idx - E;
  }
  if ((unsigned)dst >= (unsigned)N || (unsigned)src >= (unsigned)N) return;
  int pos = atomicAdd(&cursor[dst], 1);
  csr[pos] = src;
}

// --------------------------- f32 -> f16 convert ----------------------------
__global__ void cvt_f16_kernel(const float* __restrict__ src, f16* __restrict__ dst,
                               int srcRows, int dstRows, int cols, int gshift) {
  int idx = blockIdx.x * blockDim.x + threadIdx.x;
  int total = dstRows << gshift;
  if (idx >= total) return;
  int row = idx >> gshift;
  int col = (idx & ((1 << gshift) - 1)) * 4;
  float4 v = make_float4(0.f, 0.f, 0.f, 0.f);
  if (row < srcRows) v = *(const float4*)&src[(size_t)row * cols + col];
  f16x4 o = {(f16)v.x, (f16)v.y, (f16)v.z, (f16)v.w};
  *(f16x4*)&dst[(size_t)row * cols + col] = o;
}

// --------------------- GEMM1: A f32 (x), B f16 (W1 f16) --------------------
// C[M,512] = x * W1^T; A rows clamped to N-1 for pad rows (outputs unused).
// f32->f16 conversion happens in-register during staging.
__global__ __launch_bounds__(256) void gemm1_kernel(
    const float* __restrict__ A, const f16* __restrict__ Bm, f16* __restrict__ C,
    int K, int Ncols, int Nrows) {
  __shared__ f16 lA[128 * 32];
  __shared__ f16 lB[128 * 32];
  const int tid = threadIdx.x;
  const int w = tid >> 6, lane = tid & 63;
  const int wm = w >> 1, wn = w & 1;
  const int rowBase = blockIdx.y * 128;
  const int colBase = blockIdx.x * 128;
  const int lrow = lane & 15, lk = lane >> 4;
  f32x4 acc[4][4];
#pragma unroll
  for (int i = 0; i < 4; ++i)
#pragma unroll
    for (int j = 0; j < 4; ++j) acc[i][j] = (f32x4){0.f, 0.f, 0.f, 0.f};

  for (int kv = 0; kv < K; kv += 32) {
    f16x8 stA[2], stB[2];
#pragma unroll
    for (int s = 0; s < 2; ++s) {
      int q = s * 256 + tid;
      int r = q >> 2;
      int cs = (q & 3) ^ ((r >> 1) & 3);
      int row = rowBase + r;
      if (row >= Nrows) row = Nrows - 1;  // clamp: pad-row outputs unused
      const float4 v0 = *(const float4*)(A + (size_t)row * K + kv + cs * 8);
      const float4 v1 = *(const float4*)(A + (size_t)row * K + kv + cs * 8 + 4);
      f16x8 o = {(f16)v0.x, (f16)v0.y, (f16)v0.z, (f16)v0.w,
                 (f16)v1.x, (f16)v1.y, (f16)v1.z, (f16)v1.w};
      stA[s] = o;
    }
#pragma unroll
    for (int s = 0; s < 2; ++s) {
      int q = s * 256 + tid;
      int r = q >> 2;
      int cs = (q & 3) ^ ((r >> 1) & 3);
      stB[s] = *(const f16x8*)(Bm + (size_t)(colBase + r) * K + kv + cs * 8);
    }
#pragma unroll
    for (int s = 0; s < 2; ++s) *(f16x8*)&lA[(size_t)(s * 256 + tid) * 8] = stA[s];
#pragma unroll
    for (int s = 0; s < 2; ++s) *(f16x8*)&lB[(size_t)(s * 256 + tid) * 8] = stB[s];
    __syncthreads();
    f16x8 aF[4], bF[4];
#pragma unroll
    for (int i = 0; i < 4; ++i) {
      int ra = wm * 64 + i * 16 + lrow;
      aF[i] = *(const f16x8*)&lA[(ra * 4 + (lk ^ ((ra >> 1) & 3))) * 8];
      int rb = wn * 64 + i * 16 + lrow;
      bF[i] = *(const f16x8*)&lB[(rb * 4 + (lk ^ ((rb >> 1) & 3))) * 8];
    }
#pragma unroll
    for (int i = 0; i < 4; ++i)
#pragma unroll
      for (int j = 0; j < 4; ++j)
        acc[i][j] = __builtin_amdgcn_mfma_f32_16x16x32_f16(aF[i], bF[j], acc[i][j], 0, 0, 0);
    __syncthreads();
  }
#pragma unroll
  for (int i = 0; i < 4; ++i) {
    int row0 = rowBase + wm * 64 + i * 16 + lk * 4;
#pragma unroll
    for (int j = 0; j < 4; ++j) {
      int col = colBase + wn * 64 + j * 16 + lrow;
#pragma unroll
      for (int rr = 0; rr < 4; ++rr)
        C[(size_t)(row0 + rr) * Ncols + col] = (f16)acc[i][j][rr];
    }
  }
}

// ------------------------------ f16 GEMM (layer 2) -------------------------
template <int BM, int TPB>
__global__ __launch_bounds__(TPB) void gemm_f16_kernel(
    const f16* __restrict__ A, const f16* __restrict__ Bm, f16* __restrict__ C,
    int K, int Ncols) {
  __shared__ f16 lA[BM * 32];
  __shared__ f16 lB[128 * 32];
  const int tid = threadIdx.x;
  const int w = tid >> 6, lane = tid & 63;
  const int wm = w >> 1, wn = w & 1;
  const int rowBase = blockIdx.y * BM;
  const int colBase = blockIdx.x * 128;
  const int lrow = lane & 15, lk = lane >> 4;
  f32x4 acc[4][4];
#pragma unroll
  for (int i = 0; i < 4; ++i)
#pragma unroll
    for (int j = 0; j < 4; ++j) acc[i][j] = (f32x4){0.f, 0.f, 0.f, 0.f};

  for (int kv = 0; kv < K; kv += 32) {
    f16x8 stA[(BM * 4) / TPB], stB[512 / TPB];
#pragma unroll
    for (int s = 0; s < (BM * 4) / TPB; ++s) {
      int q = s * TPB + tid;
      int r = q >> 2;
      int cs = (q & 3) ^ ((r >> 1) & 3);
      stA[s] = *(const f16x8*)(A + (size_t)(rowBase + r) * K + kv + cs * 8);
    }
#pragma unroll
    for (int s = 0; s < 512 / TPB; ++s) {
      int q = s * TPB + tid;
      int r = q >> 2;
      int cs = (q & 3) ^ ((r >> 1) & 3);
      stB[s] = *(const f16x8*)(Bm + (size_t)(colBase + r) * K + kv + cs * 8);
    }
#pragma unroll
    for (int s = 0; s < (BM * 4) / TPB; ++s)
      *(f16x8*)&lA[(size_t)(s * TPB + tid) * 8] = stA[s];
#pragma unroll
    for (int s = 0; s < 512 / TPB; ++s)
      *(f16x8*)&lB[(size_t)(s * TPB + tid) * 8] = stB[s];
    __syncthreads();
    f16x8 aF[4], bF[4];
#pragma unroll
    for (int i = 0; i < 4; ++i) {
      int ra = wm * 64 + i * 16 + lrow;
      aF[i] = *(const f16x8*)&lA[(ra * 4 + (lk ^ ((ra >> 1) & 3))) * 8];
      int rb = wn * 64 + i * 16 + lrow;
      bF[i] = *(const f16x8*)&lB[(rb * 4 + (lk ^ ((rb >> 1) & 3))) * 8];
    }
#pragma unroll
    for (int i = 0; i < 4; ++i)
#pragma unroll
      for (int j = 0; j < 4; ++j)
        acc[i][j] = __builtin_amdgcn_mfma_f32_16x16x32_f16(aF[i], bF[j], acc[i][j], 0, 0, 0);
    __syncthreads();
  }
#pragma unroll
  for (int i = 0; i < 4; ++i) {
    int row0 = rowBase + wm * 64 + i * 16 + lk * 4;
#pragma unroll
    for (int j = 0; j < 4; ++j) {
      int col = colBase + wn * 64 + j * 16 + lrow;
#pragma unroll
      for (int rr = 0; rr < 4; ++rr)
        C[(size_t)(row0 + rr) * Ncols + col] = (f16)acc[i][j][rr];
    }
  }
}

// ------------------- attention coefficients a_src / a_dst ------------------
__global__ __launch_bounds__(256) void attn_coef_kernel(
    const f16* __restrict__ xw, const float* __restrict__ attS,
    const float* __restrict__ attD, float* __restrict__ aS, float* __restrict__ aD,
    int NH, int H) {
  int wg = blockIdx.x * 4 + (threadIdx.x >> 6);
  int lane = threadIdx.x & 63;
  if (wg >= NH) return;
  int h = wg & (H - 1);
  const f16x2 v = *(const f16x2*)&xw[(size_t)wg * 128 + lane * 2];
  const float2 s2 = *(const float2*)&attS[h * 128 + lane * 2];
  const float2 d2 = *(const float2*)&attD[h * 128 + lane * 2];
  float ps = (float)v[0] * s2.x + (float)v[1] * s2.y;
  float pd = (float)v[0] * d2.x + (float)v[1] * d2.y;
#pragma unroll
  for (int off = 32; off; off >>= 1) {
    ps += __shfl_xor(ps, off);
    pd += __shfl_xor(pd, off);
  }
  if (lane == 0) { aS[wg] = ps; aD[wg] = pd; }
}

// --------------------- layer-1 aggregation (per dst) -----------------------
// One wave per dst; lane owns 8 contiguous channels (f16x8 16 B gathers).
// Staging (once per 64 edges): load csr, gather aS[src] (800 KB, L2-hot),
// compute alpha = exp(leakyrelu(aS+aD)) in-register, stage (src, alpha4) to
// wave-private LDS; pad slots alpha=0/src=0. Main loop: branch-free 8-deep
// unroll (pads gather row 0, L1-hot, FMA x0). Normalize+bias+ELU in epilogue.
__global__ __launch_bounds__(256) void agg1_kernel(
    const int* __restrict__ row_ptr, const int* __restrict__ csr,
    const float* __restrict__ aS, const float* __restrict__ aD,
    const f16* __restrict__ xw, const float* __restrict__ bias,
    f16* __restrict__ A2, int n) {
  __shared__ float4 lal[4][64];
  __shared__ int lsrc[4][64];
  const int wv = threadIdx.x >> 6, lane = threadIdx.x & 63;
  const int dst = blockIdx.x * 4 + wv;
  if (dst >= n) return;
  const int beg = row_ptr[dst], end = row_ptr[dst + 1];
  const int hh = lane >> 4;  // head of this lane's 8 channels
  const float4 ad4 = *(const float4*)&aD[(size_t)dst * 4];
  f32x4 den4 = {0.f, 0.f, 0.f, 0.f};
  float acc[8] = {0.f, 0.f, 0.f, 0.f, 0.f, 0.f, 0.f, 0.f};
  const f16* __restrict__ xcol = xw + lane * 8;
  const float* __restrict__ lalf = (const float*)&lal[wv][0];

  for (int base = beg; base < end; base += 64) {
    int i = base + lane;
    int s = 0;
    float4 a4 = make_float4(0.f, 0.f, 0.f, 0.f);
    if (i < end) {
      s = csr[i];
      const float4 as4 = *(const float4*)&aS[(size_t)s * 4];
      float x0 = as4.x + ad4.x; x0 = (x0 > 0.f) ? x0 : 0.2f * x0; a4.x = __expf(x0);
      float x1 = as4.y + ad4.y; x1 = (x1 > 0.f) ? x1 : 0.2f * x1; a4.y = __expf(x1);
      float x2 = as4.z + ad4.z; x2 = (x2 > 0.f) ? x2 : 0.2f * x2; a4.z = __expf(x2);
      float x3 = as4.w + ad4.w; x3 = (x3 > 0.f) ? x3 : 0.2f * x3; a4.w = __expf(x3);
    }
    den4[0] += a4.x; den4[1] += a4.y; den4[2] += a4.z; den4[3] += a4.w;
    lsrc[wv][lane] = s;
    lal[wv][lane] = a4;
    asm volatile("s_waitcnt lgkmcnt(0)" ::: "memory");
    const int m = min(64, end - base);
    const int jm = (m + 7) & ~7;  // pad slots have alpha=0, src=0
    for (int j = 0; j < jm; j += 8) {
      int sj[8];
      float aj[8];
      f16x8 v[8];
#pragma unroll
      for (int k = 0; k < 8; ++k) {
        sj[k] = lsrc[wv][j + k];
        aj[k] = lalf[(j + k) * 4 + hh];
      }
#pragma unroll
      for (int k = 0; k < 8; ++k) v[k] = *(const f16x8*)&xcol[(size_t)sj[k] * 512];
#pragma unroll
      for (int k = 0; k < 8; ++k)
#pragma unroll
        for (int q = 0; q < 8; ++q) acc[q] = fmaf(aj[k], (float)v[k][q], acc[q]);
    }
  }
#pragma unroll
  for (int off = 32; off; off >>= 1) {
#pragma unroll
    for (int k = 0; k < 4; ++k) den4[k] += __shfl_xor(den4[k], off);
  }
  float dh = (hh == 0) ? den4[0] : (hh == 1) ? den4[1] : (hh == 2) ? den4[2] : den4[3];
  const float inv = 1.f / dh;
  const int c = lane * 8;
  const float4 b0 = *(const float4*)&bias[c];
  const float4 b1 = *(const float4*)&bias[c + 4];
  const float bb[8] = {b0.x, b0.y, b0.z, b0.w, b1.x, b1.y, b1.z, b1.w};
  f16x8 o;
#pragma unroll
  for (int q = 0; q < 8; ++q) {
    float vv = acc[q] * inv + bb[q];
    vv = (vv > 0.f) ? vv : (__expf(vv) - 1.f);
    o[q] = (f16)vv;
  }
  *(f16x8*)&A2[(size_t)dst * 512 + c] = o;
}

// ------------- layer-2 aggregation + ELU + fused classifier ----------------
// One wave per dst (C=128): 2 edges/iter (half=lane>>5, 32 lanes x f16x4),
// alpha fused into staging; branch-free 8-pair unroll via alpha=0 pads.
__global__ __launch_bounds__(256) void agg2_kernel(
    const int* __restrict__ row_ptr, const int* __restrict__ csr,
    const float* __restrict__ aS, const float* __restrict__ aD,
    const f16* __restrict__ xw2, const float* __restrict__ b2,
    const float* __restrict__ Wc, const float* __restrict__ bc,
    float* __restrict__ out, int n) {
  __shared__ float2 led[4][64];
  const int wv = threadIdx.x >> 6, lane = threadIdx.x & 63;
  const int dst = blockIdx.x * 4 + wv;
  if (dst >= n) return;
  const int beg = row_ptr[dst], end = row_ptr[dst + 1];
  const int half = lane >> 5, lc = lane & 31;
  const float ad = aD[dst];
  float den = 0.f;
  float acc[4] = {0.f, 0.f, 0.f, 0.f};
  const f16* __restrict__ xrow = xw2 + lc * 4;

  for (int base = beg; base < end; base += 64) {
    int i = base + lane;
    float2 pa = make_float2(__int_as_float(0), 0.f);
    if (i < end) {
      int s = csr[i];
      float x = aS[s] + ad;
      x = (x > 0.f) ? x : 0.2f * x;
      pa = make_float2(__int_as_float(s), __expf(x));
    }
    den += pa.y;
    led[wv][lane] = pa;
    asm volatile("s_waitcnt lgkmcnt(0)" ::: "memory");
    const int m = min(64, end - base);
    const int pr = (((m + 1) >> 1) + 7) & ~7;  // pad pairs: alpha=0, src=0
    for (int p = 0; p < pr; p += 8) {
      int sj[8];
      float aj[8];
      f16x4 v[8];
#pragma unroll
      for (int k = 0; k < 8; ++k) {
        float2 q = led[wv][(p + k) * 2 + half];
        sj[k] = __float_as_int(q.x);
        aj[k] = q.y;
      }
#pragma unroll
      for (int k = 0; k < 8; ++k) v[k] = *(const f16x4*)&xrow[(size_t)sj[k] * 128];
#pragma unroll
      for (int k = 0; k < 8; ++k) {
        acc[0] = fmaf(aj[k], (float)v[k][0], acc[0]);
        acc[1] = fmaf(aj[k], (float)v[k][1], acc[1]);
        acc[2] = fmaf(aj[k], (float)v[k][2], acc[2]);
        acc[3] = fmaf(aj[k], (float)v[k][3], acc[3]);
      }
    }
  }
#pragma unroll
  for (int off = 32; off; off >>= 1) den += __shfl_xor(den, off);
  const float inv = 1.f / den;
#pragma unroll
  for (int k = 0; k < 4; ++k) acc[k] += __shfl_xor(acc[k], 32);
  const int c = lc * 4;
  const float4 bb = *(const float4*)&b2[c];
  const float4 w0 = *(const float4*)&Wc[c];
  const float4 w1 = *(const float4*)&Wc[128 + c];
  const float bv[4] = {bb.x, bb.y, bb.z, bb.w};
  const float w0v[4] = {w0.x, w0.y, w0.z, w0.w};
  const float w1v[4] = {w1.x, w1.y, w1.z, w1.w};
  float l0 = 0.f, l1 = 0.f;
#pragma unroll
  for (int k = 0; k < 4; ++k) {
    float vv = acc[k] * inv + bv[k];
    vv = (vv > 0.f) ? vv : (__expf(vv) - 1.f);
    l0 = fmaf(vv, w0v[k], l0);
    l1 = fmaf(vv, w1v[k], l1);
  }
#pragma unroll
  for (int off = 16; off; off >>= 1) {
    l0 += __shfl_xor(l0, off);
    l1 += __shfl_xor(l1, off);
  }
  if (lane == 0) {
    out[dst * 2] = l0 + bc[0];
    out[dst * 2 + 1] = l1 + bc[1];
  }
}

// ---------------------------------------------------------------------------

extern "C" void kernel_launch(void* const* d_in, const int* in_sizes, int n_in,
                              void* d_out, int out_size, void* d_ws, size_t ws_size,
                              hipStream_t stream) {
  const float* x     = (const float*)d_in[0];
  const int*   ei    = (const int*)d_in[1];
  const float* W1    = (const float*)d_in[2];
  const float* att1s = (const float*)d_in[3];
  const float* att1d = (const float*)d_in[4];
  const float* b1    = (const float*)d_in[5];
  const float* W2    = (const float*)d_in[6];
  const float* att2s = (const float*)d_in[7];
  const float* att2d = (const float*)d_in[8];
  const float* b2    = (const float*)d_in[9];
  const float* Wc    = (const float*)d_in[10];
  const float* bc    = (const float*)d_in[11];
  float* out = (float*)d_out;

  const int N = in_sizes[0] / 256;
  const int E = in_sizes[1] / 2;
  const int EA = E + N;
  const int Mpad = (N + 127) & ~127;
  const int NB = (N + 255) / 256;
  const int EB = (EA + 255) / 256;

  char* base = (char*)d_ws;
  size_t off = 0;
  auto alloc = [&](size_t bytes) -> char* {
    char* p = base + off;
    off = (off + bytes + 255) & ~(size_t)255;
    return p;
  };
  f16* B1f  = (f16*)alloc((size_t)512 * 256 * sizeof(f16));    // W1 f16
  f16* xw1h = (f16*)alloc((size_t)Mpad * 512 * sizeof(f16));   // layer1 pre-agg
  f16* A2   = (f16*)alloc((size_t)Mpad * 512 * sizeof(f16));   // h = elu(agg1)
  f16* B2f  = (f16*)alloc((size_t)128 * 512 * sizeof(f16));    // W2 f16
  f16* xw2h = (f16*)alloc((size_t)Mpad * 128 * sizeof(f16));   // layer2 pre-agg
  float* aS1 = (float*)alloc((size_t)N * 4 * sizeof(float));
  float* aD1 = (float*)alloc((size_t)N * 4 * sizeof(float));
  float* aS2 = (float*)alloc((size_t)N * sizeof(float));
  float* aD2 = (float*)alloc((size_t)N * sizeof(float));
  int* deg     = (int*)alloc((size_t)N * sizeof(int));
  int* row_ptr = (int*)alloc((size_t)(N + 1) * sizeof(int));
  int* cursor  = (int*)alloc((size_t)N * sizeof(int));
  int* csr     = (int*)alloc((size_t)EA * sizeof(int));
  int* tmp     = (int*)alloc((size_t)N * sizeof(int));
  int* bsum    = (int*)alloc((size_t)NB * sizeof(int));
  int* boff    = (int*)alloc((size_t)NB * sizeof(int));
  int* flag    = (int*)alloc(256);
  (void)n_in; (void)out_size; (void)ws_size;

  hipMemsetAsync(deg, 0, (size_t)N * sizeof(int), stream);
  if (Mpad > N)  // zero A2 pad rows so GEMM2 pad outputs stay finite
    hipMemsetAsync(A2 + (size_t)N * 512, 0, (size_t)(Mpad - N) * 512 * sizeof(f16), stream);

  detect_i64_kernel<<<1, 64, 0, stream>>>(ei, flag);
  hist_kernel<<<EB, 256, 0, stream>>>(ei, E, N, flag, deg);
  scan1_kernel<<<NB, 256, 0, stream>>>(deg, tmp, bsum, N);
  scan2_kernel<<<1, 256, 0, stream>>>(bsum, boff, NB);
  scan3_kernel<<<NB, 256, 0, stream>>>(deg, tmp, boff, row_ptr, cursor, N);
  scatter_kernel<<<EB, 256, 0, stream>>>(ei, E, N, flag, cursor, csr);

  cvt_f16_kernel<<<(512 * 64 + 255) / 256, 256, 0, stream>>>(W1, B1f, 512, 512, 256, 6);
  cvt_f16_kernel<<<(128 * 128 + 255) / 256, 256, 0, stream>>>(W2, B2f, 128, 128, 512, 7);

  dim3 g1(4, Mpad / 128);
  gemm1_kernel<<<g1, 256, 0, stream>>>(x, B1f, xw1h, 256, 512, N);
  attn_coef_kernel<<<N, 256, 0, stream>>>(xw1h, att1s, att1d, aS1, aD1, N * 4, 4);
  agg1_kernel<<<(N + 3) / 4, 256, 0, stream>>>(row_ptr, csr, aS1, aD1, xw1h, b1, A2, N);

  dim3 g2(1, Mpad / 64);
  gemm_f16_kernel<64, 128><<<g2, 128, 0, stream>>>(A2, B2f, xw2h, 512, 128);
  attn_coef_kernel<<<(N + 3) / 4, 256, 0, stream>>>(xw2h, att2s, att2d, aS2, aD2, N, 1);
  agg2_kernel<<<(N + 3) / 4, 256, 0, stream>>>(row_ptr, csr, aS2, aD2, xw2h, b2, Wc, bc, out, N);
}